// Round 1
// baseline (441.082 us; speedup 1.0000x reference)
//
#include <hip/hip_runtime.h>

#define NEG_INF -9000000000000000.0f
#define ALPHA 0.2f

// wa[0:64]  = W @ a1   (a1 = a[0:64])
// wa[64:128]= W @ a2   (a2 = a[64:128])
__global__ void precompute_wa(const float* __restrict__ W, const float* __restrict__ a,
                              float* __restrict__ wa) {
    __shared__ float a_sh[128];
    int t = threadIdx.x; // 128 threads
    a_sh[t] = a[t];
    __syncthreads();
    if (t < 64) {
        float s1 = 0.f, s2 = 0.f;
        const float* row = W + t * 64;
#pragma unroll
        for (int h = 0; h < 64; ++h) {
            float w = row[h];
            s1 += w * a_sh[h];
            s2 += w * a_sh[64 + h];
        }
        wa[t] = s1;
        wa[64 + t] = s2;
    }
}

// One block per node n. 256 threads = 4 waves.
__global__ __launch_bounds__(256) void gat_kernel(
    const float* __restrict__ item, const float* __restrict__ ent_g,
    const int* __restrict__ adj, const float* __restrict__ wa,
    float* __restrict__ out)
{
    constexpr int LDSTRIDE = 68; // 64 + 4 pad: keeps 16B alignment, breaks bank aliasing
    __shared__ float ent[64 * LDSTRIDE];
    __shared__ float wa1_sh[64];
    __shared__ float wa2_sh[64];
    __shared__ float item_sh[64];
    __shared__ float e_sh[64];
    __shared__ float red_sh[256];
    __shared__ float s1_sh;

    const int n = blockIdx.x;
    const int t = threadIdx.x;

    if (t < 64)       wa1_sh[t]        = wa[t];
    else if (t < 128) wa2_sh[t - 64]   = wa[t];
    else if (t < 192) item_sh[t - 128] = item[(size_t)n * 64 + (t - 128)];
    __syncthreads();

    // s1 = dot(item, wa1): wave 0 butterfly
    if (t < 64) {
        float p = item_sh[t] * wa1_sh[t];
#pragma unroll
        for (int k = 1; k < 64; k <<= 1) p += __shfl_xor(p, k);
        if (t == 0) s1_sh = p;
    }

    // Phase 1: stage entity tile (16 KB) to LDS, fusing the wa2 dot.
    // Thread t owns the contiguous 64B chunk at offset t*64B of the tile:
    // row m = t>>2, quarter q = t&3.
    const int m = t >> 2;
    const int q = t & 3;
    const float4* src = (const float4*)(ent_g + (size_t)n * 4096 + t * 16);
    float* dst = &ent[m * LDSTRIDE + q * 16];
    float partial = 0.f;
#pragma unroll
    for (int i = 0; i < 4; ++i) {
        float4 v = src[i];
        ((float4*)dst)[i] = v;
        const int c = q * 16 + i * 4;
        partial += v.x * wa2_sh[c]     + v.y * wa2_sh[c + 1]
                 + v.z * wa2_sh[c + 2] + v.w * wa2_sh[c + 3];
    }
    // reduce the 4 quarter-dots for row m (lanes t, t^1, t^2 same wave)
    partial += __shfl_xor(partial, 1);
    partial += __shfl_xor(partial, 2);
    if (q == 0) e_sh[m] = partial;
    __syncthreads();

    // Phase 2: leaky-relu + mask + softmax over 64 neighbors (wave 0)
    if (t < 64) {
        float e = s1_sh + e_sh[t];
        e = e > 0.f ? e : ALPHA * e;
        if (adj[(size_t)n * 64 + t] <= 0) e = NEG_INF;
        float mx = e;
#pragma unroll
        for (int k = 1; k < 64; k <<= 1) mx = fmaxf(mx, __shfl_xor(mx, k));
        float ex = __expf(e - mx);
        float sm = ex;
#pragma unroll
        for (int k = 1; k < 64; k <<= 1) sm += __shfl_xor(sm, k);
        e_sh[t] = ex / sm;  // attention weight
    }
    __syncthreads();

    // Phase 3: out[f] = sum_m att[m] * ent[m][f] + item[f]
    // wave g handles rows g*16..g*16+15; lane = f. att read is wave-uniform broadcast;
    // ent read is 64 consecutive floats -> 2 lanes/bank (free).
    const int f = t & 63;
    const int g = t >> 6;
    float acc = 0.f;
#pragma unroll
    for (int mm = 0; mm < 16; ++mm) {
        const int row = g * 16 + mm;
        acc += e_sh[row] * ent[row * LDSTRIDE + f];
    }
    red_sh[t] = acc;
    __syncthreads();
    if (t < 64) {
        float o = red_sh[t] + red_sh[64 + t] + red_sh[128 + t] + red_sh[192 + t] + item_sh[t];
        out[(size_t)n * 64 + t] = o;
    }
}

extern "C" void kernel_launch(void* const* d_in, const int* in_sizes, int n_in,
                              void* d_out, int out_size, void* d_ws, size_t ws_size,
                              hipStream_t stream) {
    const float* item = (const float*)d_in[0];   // (N, 64)
    const float* ent  = (const float*)d_in[1];   // (N, 64, 64)
    const int*   adj  = (const int*)d_in[2];     // (N, 64)
    const float* W    = (const float*)d_in[3];   // (64, 64)
    const float* a    = (const float*)d_in[4];   // (128, 1)
    float* out = (float*)d_out;                  // (N, 64)
    float* wa  = (float*)d_ws;                   // 128 floats scratch

    const int N = in_sizes[0] / 64;

    precompute_wa<<<1, 128, 0, stream>>>(W, a, wa);
    gat_kernel<<<N, 256, 0, stream>>>(item, ent, adj, wa, out);
}

// Round 2
// 438.620 us; speedup vs baseline: 1.0056x; 1.0056x over previous
//
#include <hip/hip_runtime.h>

#define NEG_INF -9000000000000000.0f
#define ALPHA 0.2f

// wa[0:64]  = W @ a1   (a1 = a[0:64])
// wa[64:128]= W @ a2   (a2 = a[64:128])
__global__ void precompute_wa(const float* __restrict__ W, const float* __restrict__ a,
                              float* __restrict__ wa) {
    __shared__ float a_sh[128];
    int t = threadIdx.x; // 128 threads
    a_sh[t] = a[t];
    __syncthreads();
    if (t < 64) {
        float s1 = 0.f, s2 = 0.f;
        const float* row = W + t * 64;
#pragma unroll
        for (int h = 0; h < 64; ++h) {
            float w = row[h];
            s1 += w * a_sh[h];
            s2 += w * a_sh[64 + h];
        }
        wa[t] = s1;
        wa[64 + t] = s2;
    }
}

// One block per node n. 256 threads = 4 waves. 3 barriers total.
__global__ __launch_bounds__(256) void gat_kernel(
    const float* __restrict__ item, const float* __restrict__ ent_g,
    const int* __restrict__ adj, const float* __restrict__ wa,
    float* __restrict__ out)
{
    __shared__ float ent[64 * 64];       // 16 KB, unpadded (all access patterns 2-lanes/bank)
    __shared__ float item_sh[64];
    __shared__ float e_sh[64];
    __shared__ float red_sh[256];
    __shared__ float s1_sh;

    const int n = blockIdx.x;
    const int t = threadIdx.x;

    // ---- Issue ALL global loads up front (independent, overlap latency) ----
    // Entity tile: chunk c = i*256 + t -> one contiguous 4 KB per wave instruction.
    const float4* src4 = (const float4*)(ent_g + (size_t)n * 4096);
    float4 v[4];
#pragma unroll
    for (int i = 0; i < 4; ++i) v[i] = src4[i * 256 + t];

    // Per-thread wa2 quarter (L2-hot broadcast), adj + item row for wave 0.
    const int q = t & 15;
    const float4 w2 = ((const float4*)(wa + 64))[q];
    int adjv = 0;
    float p1 = 0.f;
    if (t < 64) {
        adjv = adj[(size_t)n * 64 + t];
        p1 = item[(size_t)n * 64 + t] * wa[t];   // s1 partial
    } else if (t < 128) {
        item_sh[t - 64] = item[(size_t)n * 64 + (t - 64)];
    }

    // ---- Stage tile to LDS + fused score dot from registers ----
#pragma unroll
    for (int i = 0; i < 4; ++i) {
        ((float4*)ent)[i * 256 + t] = v[i];
        // chunk c = i*256+t covers row m = i*16 + (t>>4), floats 4q..4q+3
        float p = v[i].x * w2.x + v[i].y * w2.y + v[i].z * w2.z + v[i].w * w2.w;
        p += __shfl_xor(p, 1);
        p += __shfl_xor(p, 2);
        p += __shfl_xor(p, 4);
        p += __shfl_xor(p, 8);   // reduced across the 16 lanes sharing row m
        if (q == 0) e_sh[i * 16 + (t >> 4)] = p;
    }

    // s1 = dot(item, wa1): wave 0 butterfly
    if (t < 64) {
#pragma unroll
        for (int k = 1; k < 64; k <<= 1) p1 += __shfl_xor(p1, k);
        if (t == 0) s1_sh = p1;
    }
    __syncthreads();   // ent, e_sh, s1_sh, item_sh all ready

    // ---- Softmax over 64 neighbors (wave 0; adj prefetched in-register) ----
    if (t < 64) {
        float e = s1_sh + e_sh[t];
        e = e > 0.f ? e : ALPHA * e;
        if (adjv <= 0) e = NEG_INF;
        float mx = e;
#pragma unroll
        for (int k = 1; k < 64; k <<= 1) mx = fmaxf(mx, __shfl_xor(mx, k));
        float ex = __expf(e - mx);
        float sm = ex;
#pragma unroll
        for (int k = 1; k < 64; k <<= 1) sm += __shfl_xor(sm, k);
        e_sh[t] = ex / sm;  // attention weight
    }
    __syncthreads();

    // ---- out[f] = sum_m att[m] * ent[m][f] + item[f] ----
    // wave g: rows g*16..g*16+15, lane = f. ent read: 64 consecutive floats = free.
    const int f = t & 63;
    const int g = t >> 6;
    float acc = 0.f;
#pragma unroll
    for (int mm = 0; mm < 16; ++mm) {
        const int row = g * 16 + mm;
        acc += e_sh[row] * ent[row * 64 + f];
    }
    red_sh[t] = acc;
    __syncthreads();
    if (t < 64) {
        out[(size_t)n * 64 + t] =
            red_sh[t] + red_sh[64 + t] + red_sh[128 + t] + red_sh[192 + t] + item_sh[t];
    }
}

extern "C" void kernel_launch(void* const* d_in, const int* in_sizes, int n_in,
                              void* d_out, int out_size, void* d_ws, size_t ws_size,
                              hipStream_t stream) {
    const float* item = (const float*)d_in[0];   // (N, 64)
    const float* ent  = (const float*)d_in[1];   // (N, 64, 64)
    const int*   adj  = (const int*)d_in[2];     // (N, 64)
    const float* W    = (const float*)d_in[3];   // (64, 64)
    const float* a    = (const float*)d_in[4];   // (128, 1)
    float* out = (float*)d_out;                  // (N, 64)
    float* wa  = (float*)d_ws;                   // 128 floats scratch

    const int N = in_sizes[0] / 64;

    precompute_wa<<<1, 128, 0, stream>>>(W, a, wa);
    gat_kernel<<<N, 256, 0, stream>>>(item, ent, adj, wa, out);
}